// Round 1
// 160.141 us; speedup vs baseline: 1.0629x; 1.0629x over previous
//
#include <hip/hip_runtime.h>

#define I_DIM 28
#define H_DIM 64
#define T_DIM 128
#define B_DIM 4096
#define OUT_DIM 10
#define MB 16         // batch rows per block: full 16 MFMA B-columns (was 8 + 8 zeros)
#define NTHREADS 256  // 4 waves; wave w owns gate-mtile w of each of the 4 gates
#define LOG2E 1.44269504088896340736f

typedef __attribute__((ext_vector_type(8))) short bf16x8;
typedef __attribute__((ext_vector_type(4))) float f32x4;
typedef __attribute__((ext_vector_type(4))) unsigned u32x4;

__device__ __forceinline__ float bfbits2f(unsigned b16) {
    return __builtin_bit_cast(float, b16 << 16);
}
// rne-rounded fp32 bits (bf16 lives in top 16 after the add)
__device__ __forceinline__ unsigned rne_u(float f) {
    unsigned u = __builtin_bit_cast(unsigned, f);
    return u + 0x7FFFu + ((u >> 16) & 1u);
}
// pack two floats -> (bf16(b)<<16)|bf16(a) : 2 rne-adds + 1 v_perm
__device__ __forceinline__ unsigned pack_pair(float a, float b) {
    return __builtin_amdgcn_perm(rne_u(b), rne_u(a), 0x07060302u);
}
__device__ __forceinline__ unsigned f2bf_rne(float f) { return rne_u(f) >> 16; }
__device__ __forceinline__ unsigned ftrunc_bf(float f) {
    return __builtin_bit_cast(unsigned, f) >> 16;
}

// 8 floats -> single rne-bf16 frag (4 dwords)
__device__ __forceinline__ bf16x8 pack_frag(const float* v) {
    u32x4 w;
    #pragma unroll
    for (int i = 0; i < 4; ++i) w[i] = pack_pair(v[2*i], v[2*i+1]);
    return __builtin_bit_cast(bf16x8, w);
}

// 8 floats -> hi/lo bf16 frags (used for W_ih only; startup)
__device__ __forceinline__ void split_frag(const float* v, bf16x8& hi, bf16x8& lo) {
    unsigned hb[8], lb[8];
    #pragma unroll
    for (int j = 0; j < 8; ++j) {
        hb[j] = f2bf_rne(v[j]);
        float rem = v[j] - bfbits2f(hb[j]);
        lb[j] = ftrunc_bf(rem);
    }
    u32x4 hw, lw;
    #pragma unroll
    for (int i = 0; i < 4; ++i) {
        hw[i] = (hb[2*i+1] << 16) | (hb[2*i] & 0xFFFFu);
        lw[i] = (lb[2*i+1] << 16) | (lb[2*i] & 0xFFFFu);
    }
    hi = __builtin_bit_cast(bf16x8, hw);
    lo = __builtin_bit_cast(bf16x8, lw);
}

__device__ __forceinline__ float fast_rcp(float v) { return __builtin_amdgcn_rcpf(v); }
__device__ __forceinline__ float exp2_f(float v)  { return __builtin_amdgcn_exp2f(v); }
__device__ __forceinline__ float sigmoid_s(float zs) {           // zs = LOG2E*z
    return fast_rcp(1.0f + exp2_f(-zs));
}
__device__ __forceinline__ float tanh_gs(float zs) {             // LOG2E*tanh(z)
    float t = fast_rcp(exp2_f(zs + zs) + 1.0f);
    return fmaf(-2.0f * LOG2E, t, LOG2E);
}
__device__ __forceinline__ float tanh_cs(float cs) {             // tanh(c), cs=LOG2E*c
    float t = fast_rcp(exp2_f(cs + cs) + 1.0f);
    return fmaf(-2.0f, t, 1.0f);
}

#define MFMA(A, B, C) __builtin_amdgcn_mfma_f32_16x16x32_bf16((A), (B), (C), 0, 0, 0)

__global__ __launch_bounds__(NTHREADS, 1)
void lstm_mfma_kernel(const float* __restrict__ x,
                      const float* __restrict__ W_ih,
                      const float* __restrict__ W_hh,
                      const float* __restrict__ b_ih,
                      const float* __restrict__ b_hh,
                      const float* __restrict__ W_out,
                      const float* __restrict__ b_out,
                      float* __restrict__ out)
{
    const int tid  = threadIdx.x;
    const int wv   = tid >> 6;        // wave 0..3
    const int lane = tid & 63;
    const int q    = lane >> 4;       // quad
    const int cm   = lane & 15;       // batch column (all 16 real now)
    const int b0   = blockIdx.x * MB;

    // h state, single rne-bf16, B-frag dword order, double-buffered. 16 real cols.
    __shared__ __align__(16) unsigned hbuf[2][512];
    // x B-frags for the chunk's two timesteps (single bf16)
    __shared__ __align__(16) unsigned xbuf[2][256];

    // ---- resident A-frags (weights, pre-scaled by LOG2E):
    // W_hh single rne-bf16 (2 MFMAs/gate); W_ih hi/lo split (2 MFMAs/gate/tt)
    bf16x8 Whh[4][2], Wih_hi[4], Wih_lo[4];
    f32x4  bias_c[4];
    #pragma unroll
    for (int g = 0; g < 4; ++g) {
        const int gn = (wv + 4 * g) * 16 + cm;     // global gate row
        #pragma unroll
        for (int kt = 0; kt < 2; ++kt) {
            const float* wr = W_hh + gn * H_DIM + kt * 32 + q * 8;
            float wt[8];
            float4 wa = *(const float4*)wr;
            float4 wb = *(const float4*)(wr + 4);
            wt[0]=wa.x*LOG2E; wt[1]=wa.y*LOG2E; wt[2]=wa.z*LOG2E; wt[3]=wa.w*LOG2E;
            wt[4]=wb.x*LOG2E; wt[5]=wb.y*LOG2E; wt[6]=wb.z*LOG2E; wt[7]=wb.w*LOG2E;
            Whh[g][kt] = pack_frag(wt);
        }
        {
            const float* ir = W_ih + gn * I_DIM + q * 8;
            float wt[8];
            float4 ia = *(const float4*)ir;
            wt[0]=ia.x*LOG2E; wt[1]=ia.y*LOG2E; wt[2]=ia.z*LOG2E; wt[3]=ia.w*LOG2E;
            if (q < 3) {
                float4 ib = *(const float4*)(ir + 4);
                wt[4]=ib.x*LOG2E; wt[5]=ib.y*LOG2E; wt[6]=ib.z*LOG2E; wt[7]=ib.w*LOG2E;
            } else { wt[4]=0.f; wt[5]=0.f; wt[6]=0.f; wt[7]=0.f; }
            split_frag(wt, Wih_hi[g], Wih_lo[g]);
        }
        #pragma unroll
        for (int r = 0; r < 4; ++r) {
            const int row = g * H_DIM + wv * 16 + 4 * q + r;
            bias_c[g][r] = (b_ih[row] + b_hh[row]) * LOG2E;
        }
    }

    // zero h buffers (h0 = 0)
    for (int i = tid; i < 1024; i += NTHREADS)
        ((unsigned*)hbuf)[i] = 0u;

    // ---- x pointers (waves 0,1 handle t = 2*chunk + wv), hoisted addressing
    const float* xp = x + ((size_t)(b0 + cm) * T_DIM + wv) * I_DIM + q * 8;
    const float* const xp_last = x + ((size_t)(b0 + cm) * T_DIM + (T_DIM - 1)) * I_DIM + q * 8;

    auto load_from = [&](const float* p, float4& xa, float4& xb) {
        xa = *(const float4*)p;
        if (q < 3) xb = *(const float4*)(p + 4);
        else       xb = float4{0.f, 0.f, 0.f, 0.f};   // I=28 pad to K=32
    };

    float4 xa_cur{0,0,0,0}, xb_cur{0,0,0,0};
    if (wv < 2) load_from(xp, xa_cur, xb_cur);

    f32x4 c_st = {0.f, 0.f, 0.f, 0.f};   // scaled cell state (LOG2E*c), 4 cells/lane
    // h write dword: rows wv*16+4q+r, col cm -> b64 of two packed pairs
    const int hdw = 256 * (wv >> 1) + 64 * (2 * (wv & 1) + (q >> 1))
                  + 4 * cm + 2 * (q & 1);

    for (int ch = 0; ch < T_DIM / 2; ++ch) {
        // prefetch next chunk's x, then pack+store current (single bf16)
        float4 xa_nxt{0,0,0,0}, xb_nxt{0,0,0,0};
        if (wv < 2) {
            const float* pn = (ch < T_DIM / 2 - 1) ? xp + 2 * I_DIM : xp_last;
            load_from(pn, xa_nxt, xb_nxt);
            xp = pn;
            u32x4 w;
            w[0] = pack_pair(xa_cur.x, xa_cur.y);
            w[1] = pack_pair(xa_cur.z, xa_cur.w);
            w[2] = pack_pair(xb_cur.x, xb_cur.y);
            w[3] = pack_pair(xb_cur.z, xb_cur.w);
            *(u32x4*)&xbuf[wv][lane * 4] = w;
        }
        __syncthreads();   // xbuf visible; also orders prev step-1 h writes

        // xw = (LOG2E*Wih) * x^T + scaled bias, both timesteps (in registers)
        f32x4 xw[2][4];
        #pragma unroll
        for (int tt = 0; tt < 2; ++tt) {
            bf16x8 X = __builtin_bit_cast(bf16x8, *(u32x4*)&xbuf[tt][lane * 4]);
            #pragma unroll
            for (int g = 0; g < 4; ++g) {
                f32x4 a = MFMA(Wih_hi[g], X, bias_c[g]);
                a = MFMA(Wih_lo[g], X, a);
                xw[tt][g] = a;
            }
        }

        // two recurrence steps: tt=0 reads hbuf[0] writes hbuf[1]; tt=1 reverse
        #pragma unroll
        for (int tt = 0; tt < 2; ++tt) {
            const int rb = tt, wb = tt ^ 1;
            if (tt == 1) __syncthreads();   // h(t) writes visible

            bf16x8 H0 = __builtin_bit_cast(bf16x8, *(u32x4*)&hbuf[rb][lane * 4]);
            bf16x8 H1 = __builtin_bit_cast(bf16x8, *(u32x4*)&hbuf[rb][256 + lane * 4]);

            f32x4 acc[4];
            #pragma unroll
            for (int g = 0; g < 4; ++g) {
                f32x4 a = MFMA(Whh[g][0], H0, xw[tt][g]);
                a = MFMA(Whh[g][1], H1, a);
                acc[g] = a;
            }

            // update 4 cells directly (rows 4q..4q+3, col cm) — no DPP shuffle
            __builtin_amdgcn_s_setprio(1);
            float hh[4];
            #pragma unroll
            for (int r = 0; r < 4; ++r) {
                float ig = sigmoid_s(acc[0][r]);
                float fg = sigmoid_s(acc[1][r]);
                float gs = tanh_gs (acc[2][r]);
                float og = sigmoid_s(acc[3][r]);
                float cc = fmaf(fg, c_st[r], ig * gs);
                c_st[r] = cc;
                hh[r] = og * tanh_cs(cc);
            }
            uint2 hw2;
            hw2.x = pack_pair(hh[0], hh[1]);
            hw2.y = pack_pair(hh[2], hh[3]);
            *(uint2*)&hbuf[wb][hdw] = hw2;
            __builtin_amdgcn_s_setprio(0);
        }
        xa_cur = xa_nxt; xb_cur = xb_nxt;
    }

    __syncthreads();

    // ---- output head: final h(T) is in hbuf[0] (T even)
    if (tid < MB * OUT_DIM) {
        const int bb = tid / OUT_DIM;
        const int o  = tid % OUT_DIM;
        float s = b_out[o];
        const float* wo = W_out + o * H_DIM;
        #pragma unroll
        for (int u = 0; u < H_DIM; ++u) {
            const int dw = 256 * (u >> 5) + 64 * ((u >> 3) & 3) + 4 * bb + ((u >> 1) & 3);
            const int sh = (u & 1) * 16;
            float h = bfbits2f((hbuf[0][dw] >> sh) & 0xFFFFu);
            s += h * wo[u];
        }
        out[(size_t)(b0 + bb) * OUT_DIM + o] = s;
    }
}

extern "C" void kernel_launch(void* const* d_in, const int* in_sizes, int n_in,
                              void* d_out, int out_size, void* d_ws, size_t ws_size,
                              hipStream_t stream) {
    const float* x     = (const float*)d_in[0];
    const float* W_ih  = (const float*)d_in[1];
    const float* W_hh  = (const float*)d_in[2];
    const float* b_ih  = (const float*)d_in[3];
    const float* b_hh  = (const float*)d_in[4];
    const float* W_out = (const float*)d_in[5];
    const float* b_out = (const float*)d_in[6];
    float* out = (float*)d_out;

    dim3 grid(B_DIM / MB);    // 256 blocks -> 1 per CU, full 16-col MFMAs
    dim3 block(NTHREADS);     // 4 waves (1 per SIMD)
    lstm_mfma_kernel<<<grid, block, 0, stream>>>(
        x, W_ih, W_hh, b_ih, b_hh, W_out, b_out, out);
}

// Round 2
// 158.410 us; speedup vs baseline: 1.0745x; 1.0109x over previous
//
#include <hip/hip_runtime.h>

#define I_DIM 28
#define H_DIM 64
#define T_DIM 128
#define B_DIM 4096
#define OUT_DIM 10
#define MB 16         // batch rows per block: full 16 MFMA B-columns
#define NTHREADS 256  // 4 waves; wave w owns gate-mtile w of each of the 4 gates
#define LOG2E 1.44269504088896340736f

typedef __attribute__((ext_vector_type(8))) short bf16x8;
typedef __attribute__((ext_vector_type(4))) float f32x4;
typedef __attribute__((ext_vector_type(4))) unsigned u32x4;

__device__ __forceinline__ float bfbits2f(unsigned b16) {
    return __builtin_bit_cast(float, b16 << 16);
}
// rne-rounded fp32 bits (bf16 lives in top 16 after the add)
__device__ __forceinline__ unsigned rne_u(float f) {
    unsigned u = __builtin_bit_cast(unsigned, f);
    return u + 0x7FFFu + ((u >> 16) & 1u);
}
// pack two floats -> (bf16(b)<<16)|bf16(a) : 2 rne-adds + 1 v_perm
__device__ __forceinline__ unsigned pack_pair(float a, float b) {
    return __builtin_amdgcn_perm(rne_u(b), rne_u(a), 0x07060302u);
}
__device__ __forceinline__ unsigned f2bf_rne(float f) { return rne_u(f) >> 16; }
__device__ __forceinline__ unsigned ftrunc_bf(float f) {
    return __builtin_bit_cast(unsigned, f) >> 16;
}

// 8 floats -> single rne-bf16 frag (4 dwords)
__device__ __forceinline__ bf16x8 pack_frag(const float* v) {
    u32x4 w;
    #pragma unroll
    for (int i = 0; i < 4; ++i) w[i] = pack_pair(v[2*i], v[2*i+1]);
    return __builtin_bit_cast(bf16x8, w);
}

// 8 floats -> hi/lo bf16 frags (used for W_ih only; startup)
__device__ __forceinline__ void split_frag(const float* v, bf16x8& hi, bf16x8& lo) {
    unsigned hb[8], lb[8];
    #pragma unroll
    for (int j = 0; j < 8; ++j) {
        hb[j] = f2bf_rne(v[j]);
        float rem = v[j] - bfbits2f(hb[j]);
        lb[j] = ftrunc_bf(rem);
    }
    u32x4 hw, lw;
    #pragma unroll
    for (int i = 0; i < 4; ++i) {
        hw[i] = (hb[2*i+1] << 16) | (hb[2*i] & 0xFFFFu);
        lw[i] = (lb[2*i+1] << 16) | (lb[2*i] & 0xFFFFu);
    }
    hi = __builtin_bit_cast(bf16x8, hw);
    lo = __builtin_bit_cast(bf16x8, lw);
}

__device__ __forceinline__ float fast_rcp(float v) { return __builtin_amdgcn_rcpf(v); }
__device__ __forceinline__ float exp2_f(float v)  { return __builtin_amdgcn_exp2f(v); }
__device__ __forceinline__ float sigmoid_s(float zs) {           // zs = LOG2E*z
    return fast_rcp(1.0f + exp2_f(-zs));
}
__device__ __forceinline__ float tanh_gs(float zs) {             // LOG2E*tanh(z)
    float t = fast_rcp(exp2_f(zs + zs) + 1.0f);
    return fmaf(-2.0f * LOG2E, t, LOG2E);
}
__device__ __forceinline__ float tanh_cs(float cs) {             // tanh(c), cs=LOG2E*c
    float t = fast_rcp(exp2_f(cs + cs) + 1.0f);
    return fmaf(-2.0f, t, 1.0f);
}

#define MFMA(A, B, C) __builtin_amdgcn_mfma_f32_16x16x32_bf16((A), (B), (C), 0, 0, 0)

// Raw barrier with counted wait: LDS writes must be visible (lgkmcnt(0)),
// but global loads (x prefetch) stay in flight across the barrier.
// __syncthreads() would emit s_waitcnt vmcnt(0) and drain the prefetch.
#define BAR() do {                                              \
    asm volatile("s_waitcnt lgkmcnt(0)" ::: "memory");          \
    __builtin_amdgcn_s_barrier();                               \
} while (0)

__global__ __launch_bounds__(NTHREADS, 1)
void lstm_mfma_kernel(const float* __restrict__ x,
                      const float* __restrict__ W_ih,
                      const float* __restrict__ W_hh,
                      const float* __restrict__ b_ih,
                      const float* __restrict__ b_hh,
                      const float* __restrict__ W_out,
                      const float* __restrict__ b_out,
                      float* __restrict__ out)
{
    const int tid  = threadIdx.x;
    const int wv   = tid >> 6;        // wave 0..3
    const int lane = tid & 63;
    const int q    = lane >> 4;       // quad
    const int cm   = lane & 15;       // batch column (all 16 real)
    const int b0   = blockIdx.x * MB;

    // h state, single rne-bf16, B-frag dword order, double-buffered.
    __shared__ __align__(16) unsigned hbuf[2][512];
    // x B-frags for the NEXT chunk's two timesteps (single bf16)
    __shared__ __align__(16) unsigned xbuf[2][256];

    // ---- resident A-frags (weights, pre-scaled by LOG2E):
    // W_hh single rne-bf16 (2 MFMAs/gate); W_ih hi/lo split (2 MFMAs/gate/tt)
    bf16x8 Whh[4][2], Wih_hi[4], Wih_lo[4];
    f32x4  bias_c[4];
    #pragma unroll
    for (int g = 0; g < 4; ++g) {
        const int gn = (wv + 4 * g) * 16 + cm;     // global gate row
        #pragma unroll
        for (int kt = 0; kt < 2; ++kt) {
            const float* wr = W_hh + gn * H_DIM + kt * 32 + q * 8;
            float wt[8];
            float4 wa = *(const float4*)wr;
            float4 wb = *(const float4*)(wr + 4);
            wt[0]=wa.x*LOG2E; wt[1]=wa.y*LOG2E; wt[2]=wa.z*LOG2E; wt[3]=wa.w*LOG2E;
            wt[4]=wb.x*LOG2E; wt[5]=wb.y*LOG2E; wt[6]=wb.z*LOG2E; wt[7]=wb.w*LOG2E;
            Whh[g][kt] = pack_frag(wt);
        }
        {
            const float* ir = W_ih + gn * I_DIM + q * 8;
            float wt[8];
            float4 ia = *(const float4*)ir;
            wt[0]=ia.x*LOG2E; wt[1]=ia.y*LOG2E; wt[2]=ia.z*LOG2E; wt[3]=ia.w*LOG2E;
            if (q < 3) {
                float4 ib = *(const float4*)(ir + 4);
                wt[4]=ib.x*LOG2E; wt[5]=ib.y*LOG2E; wt[6]=ib.z*LOG2E; wt[7]=ib.w*LOG2E;
            } else { wt[4]=0.f; wt[5]=0.f; wt[6]=0.f; wt[7]=0.f; }
            split_frag(wt, Wih_hi[g], Wih_lo[g]);
        }
        #pragma unroll
        for (int r = 0; r < 4; ++r) {
            const int row = g * H_DIM + wv * 16 + 4 * q + r;
            bias_c[g][r] = (b_ih[row] + b_hh[row]) * LOG2E;
        }
    }

    // zero h buffers (h0 = 0)
    for (int i = tid; i < 1024; i += NTHREADS)
        ((unsigned*)hbuf)[i] = 0u;

    // ---- x pointers (waves 0,1 handle t = 2*chunk + wv)
    const float* xp = x + ((size_t)(b0 + cm) * T_DIM + wv) * I_DIM + q * 8;
    const float* const xp_last = x + ((size_t)(b0 + cm) * T_DIM + (T_DIM - 1)) * I_DIM + q * 8;

    auto load_from = [&](const float* p, float4& xa, float4& xb) {
        xa = *(const float4*)p;
        if (q < 3) xb = *(const float4*)(p + 4);
        else       xb = float4{0.f, 0.f, 0.f, 0.f};   // I=28 pad to K=32
    };
    auto pack_store_x = [&](const float4& xa, const float4& xb) {
        u32x4 w;
        w[0] = pack_pair(xa.x, xa.y);
        w[1] = pack_pair(xa.z, xa.w);
        w[2] = pack_pair(xb.x, xb.y);
        w[3] = pack_pair(xb.z, xb.w);
        *(u32x4*)&xbuf[wv][lane * 4] = w;
    };

    // ---- prologue: xbuf <- x(chunk 0); xw_cur <- xw(chunk 0); prefetch x(chunk 1)
    float4 xa0{0,0,0,0}, xb0{0,0,0,0};
    if (wv < 2) { load_from(xp, xa0, xb0); pack_store_x(xa0, xb0); }
    __syncthreads();

    f32x4 xw_cur[2][4];
    #pragma unroll
    for (int tt = 0; tt < 2; ++tt) {
        bf16x8 X = __builtin_bit_cast(bf16x8, *(u32x4*)&xbuf[tt][lane * 4]);
        #pragma unroll
        for (int g = 0; g < 4; ++g) {
            f32x4 a = MFMA(Wih_hi[g], X, bias_c[g]);
            a = MFMA(Wih_lo[g], X, a);
            xw_cur[tt][g] = a;
        }
    }

    float4 xa_cur{0,0,0,0}, xb_cur{0,0,0,0};
    if (wv < 2) { xp += 2 * I_DIM; load_from(xp, xa_cur, xb_cur); }  // x(chunk 1)

    f32x4 c_st = {0.f, 0.f, 0.f, 0.f};   // scaled cell state (LOG2E*c), 4 cells/lane
    // h write dword: rows wv*16+4q+r, col cm -> b64 of two packed pairs
    const int hdw = 256 * (wv >> 1) + 64 * (2 * (wv & 1) + (q >> 1))
                  + 4 * cm + 2 * (q & 1);

    for (int ch = 0; ch < T_DIM / 2; ++ch) {
        // pack x(ch+1) into xbuf (loads issued last iteration; the compiler's
        // vmcnt wait lands HERE, a full chunk after issue -> effectively free)
        if (wv < 2) pack_store_x(xa_cur, xb_cur);
        BAR();   // xbuf(ch+1) visible; hbuf[0] writes from prev tt=1 visible

        // issue x(ch+2) load now; it stays in flight across both barriers
        float4 xa_nxt{0,0,0,0}, xb_nxt{0,0,0,0};
        if (wv < 2) {
            const float* pn = (ch < T_DIM / 2 - 2) ? xp + 2 * I_DIM : xp_last;
            load_from(pn, xa_nxt, xb_nxt);
            xp = pn;
        }

        // X frags for xw(ch+1): both read here, before the tt=1 barrier, so
        // reads and next chunk's writes are in disjoint barrier intervals.
        bf16x8 X0 = __builtin_bit_cast(bf16x8, *(u32x4*)&xbuf[0][lane * 4]);
        bf16x8 X1 = __builtin_bit_cast(bf16x8, *(u32x4*)&xbuf[1][lane * 4]);

        f32x4 xw_nxt[2][4];
        #pragma unroll
        for (int tt = 0; tt < 2; ++tt) {
            const int rb = tt, wb = tt ^ 1;
            if (tt == 1) BAR();   // h(t) writes visible

            bf16x8 H0 = __builtin_bit_cast(bf16x8, *(u32x4*)&hbuf[rb][lane * 4]);
            bf16x8 H1 = __builtin_bit_cast(bf16x8, *(u32x4*)&hbuf[rb][256 + lane * 4]);

            // recurrence MFMAs (critical path)
            f32x4 acc[4];
            #pragma unroll
            for (int g = 0; g < 4; ++g) {
                f32x4 a = MFMA(Whh[g][0], H0, xw_cur[tt][g]);
                a = MFMA(Whh[g][1], H1, a);
                acc[g] = a;
            }
            // xw(ch+1) for this tt: independent MFMAs, fill the pipe while the
            // activation chain runs
            bf16x8 X = (tt == 0) ? X0 : X1;
            #pragma unroll
            for (int g = 0; g < 4; ++g) {
                f32x4 a = MFMA(Wih_hi[g], X, bias_c[g]);
                a = MFMA(Wih_lo[g], X, a);
                xw_nxt[tt][g] = a;
            }

            // update 4 cells directly (rows 4q..4q+3, col cm)
            float hh[4];
            #pragma unroll
            for (int r = 0; r < 4; ++r) {
                float ig = sigmoid_s(acc[0][r]);
                float fg = sigmoid_s(acc[1][r]);
                float gs = tanh_gs (acc[2][r]);
                float og = sigmoid_s(acc[3][r]);
                float cc = fmaf(fg, c_st[r], ig * gs);
                c_st[r] = cc;
                hh[r] = og * tanh_cs(cc);
            }
            uint2 hw2;
            hw2.x = pack_pair(hh[0], hh[1]);
            hw2.y = pack_pair(hh[2], hh[3]);
            *(uint2*)&hbuf[wb][hdw] = hw2;
        }

        #pragma unroll
        for (int tt = 0; tt < 2; ++tt)
            #pragma unroll
            for (int g = 0; g < 4; ++g)
                xw_cur[tt][g] = xw_nxt[tt][g];
        xa_cur = xa_nxt; xb_cur = xb_nxt;
    }

    __syncthreads();   // full drain once; orders final hbuf[0] writes

    // ---- output head: final h(T) is in hbuf[0] (T even)
    if (tid < MB * OUT_DIM) {
        const int bb = tid / OUT_DIM;
        const int o  = tid % OUT_DIM;
        float s = b_out[o];
        const float* wo = W_out + o * H_DIM;
        #pragma unroll
        for (int u = 0; u < H_DIM; ++u) {
            const int dw = 256 * (u >> 5) + 64 * ((u >> 3) & 3) + 4 * bb + ((u >> 1) & 3);
            const int sh = (u & 1) * 16;
            float h = bfbits2f((hbuf[0][dw] >> sh) & 0xFFFFu);
            s += h * wo[u];
        }
        out[(size_t)(b0 + bb) * OUT_DIM + o] = s;
    }
}

extern "C" void kernel_launch(void* const* d_in, const int* in_sizes, int n_in,
                              void* d_out, int out_size, void* d_ws, size_t ws_size,
                              hipStream_t stream) {
    const float* x     = (const float*)d_in[0];
    const float* W_ih  = (const float*)d_in[1];
    const float* W_hh  = (const float*)d_in[2];
    const float* b_ih  = (const float*)d_in[3];
    const float* b_hh  = (const float*)d_in[4];
    const float* W_out = (const float*)d_in[5];
    const float* b_out = (const float*)d_in[6];
    float* out = (float*)d_out;

    dim3 grid(B_DIM / MB);    // 256 blocks -> 1 per CU, full 16-col MFMAs
    dim3 block(NTHREADS);     // 4 waves (1 per SIMD)
    lstm_mfma_kernel<<<grid, block, 0, stream>>>(
        x, W_ih, W_hh, b_ih, b_hh, W_out, b_out, out);
}